// Round 3
// baseline (30053.152 us; speedup 1.0000x reference)
//
#include <hip/hip_runtime.h>

// Problem constants
#define BD   64      // batch per direction
#define DD   2048
#define HH   4096
#define NSS  25
#define BBr  128     // combined rows (fwd 0..63, bwd 64..127)

typedef _Float16 halfx8 __attribute__((ext_vector_type(8)));
typedef float    floatx4 __attribute__((ext_vector_type(4)));

__device__ __forceinline__ unsigned short f2h_bits(float x) {
    union { _Float16 h; unsigned short u; } c;
    c.h = (_Float16)x;
    return c.u;
}

// ---------------------------------------------------------------------------
// init: state + first A-operand (mom-type: [pos | sin(pos)])
// ---------------------------------------------------------------------------
__global__ void init_kernel(const float* __restrict__ position,
                            const float* __restrict__ momf,
                            const float* __restrict__ momb,
                            float* __restrict__ pos, float* __restrict__ mom,
                            float* __restrict__ sld,
                            unsigned short* __restrict__ Abuf) {
    int idx = blockIdx.x * 256 + threadIdx.x;   // over BBr*DD
    int r = idx >> 11, d = idx & 2047;
    float p = position[((r & 63) << 11) + d];
    pos[idx] = p;
    mom[idx] = (r < 64) ? momf[(r << 11) + d] : momb[((r - 64) << 11) + d];
    Abuf[(r << 12) + d]        = f2h_bits(p);
    Abuf[(r << 12) + 2048 + d] = f2h_bits(sinf(p));
    if (idx < BBr) sld[idx] = 0.f;
}

// ---------------------------------------------------------------------------
// Weight conversion: fp32 (rows x cols, ldi) -> f16 transposed (cols x rows, ldo)
// 32x32 LDS tile. grid: (cols/32, rows/32), 256 threads.
// ---------------------------------------------------------------------------
__global__ __launch_bounds__(256) void transpose_cvt_kernel(
        const float* __restrict__ src, int ldi,
        unsigned short* __restrict__ dst, int ldo) {
    __shared__ float tile[32][33];
    const int rb = blockIdx.y * 32;   // src row base
    const int cb = blockIdx.x * 32;   // src col base
    const int t  = threadIdx.x;
    const int r  = t >> 3;
    const int c4 = (t & 7) * 4;
    float4 v = *reinterpret_cast<const float4*>(src + (size_t)(rb + r) * ldi + cb + c4);
    tile[r][c4 + 0] = v.x; tile[r][c4 + 1] = v.y;
    tile[r][c4 + 2] = v.z; tile[r][c4 + 3] = v.w;
    __syncthreads();
    union { unsigned short us[4]; uint2 v; } pk;
#pragma unroll
    for (int j = 0; j < 4; ++j) pk.us[j] = f2h_bits(tile[c4 + j][r]);
    *reinterpret_cast<uint2*>(dst + (size_t)(cb + r) * ldo + rb + c4) = pk.v;
}

// ---------------------------------------------------------------------------
// Pipelined GEMM: C(128 x N) = A(128 x K, f16 row-major) @ BT(N x K, f16)^T
// Block: 256 thr = 4 waves; tile 128 rows x 16 cols; BK=128 chunk.
// Reg-staged double-buffered LDS pipeline (T14 issue-early/write-late):
//   per chunk: each thread global-loads 8x16B of A + 1x16B of B into regs
//   BEFORE the MFMA section (HBM/L2 latency hides under compute), then
//   ds_write_b128 AFTER it into the other buffer; one barrier per chunk
//   provides write->read ordering across the double buffer.
// LDS layout (per buffer): A rows 0..127 at row*128, B rows 0..15 at
// 16384+row*128; within a 256B row of 16 16B slots, phys = slot ^ (row&7)
// (XOR swizzle on BOTH write and read -> uniform 8-lanes-per-4-bank-group,
// the ds_*_b128 minimum; without it the fixed-column read at stride 256B
// would be a wide bank conflict).
// EPI 0: relu(+b1 + t@Wt) -> f16 ; EPI 1: relu(+bh) -> f16 ; EPI 2: raw fp32
// ---------------------------------------------------------------------------
template <int EPI>
__global__ __launch_bounds__(256) void gemm_lds_kernel(
        const unsigned short* __restrict__ A, int lda, int K,
        const unsigned short* __restrict__ BT,
        void* __restrict__ Cout, int ldc,
        const float* __restrict__ biasp, const float* __restrict__ Wtn,
        const float* __restrict__ ts, int sF, int sB) {
    // per buffer: A = 16384 shorts (128 rows * 128), B = 2048 shorts (16 * 128)
    __shared__ unsigned short lds[2 * 18432];   // 72 KB

    const int tid  = threadIdx.x;
    const int w    = tid >> 6;       // wave 0..3
    const int lane = tid & 63;
    const int hi   = lane >> 4;      // 0..3  (= qd)
    const int lo   = lane & 15;      // 0..15 (= fl)
    const int fq   = lo & 7;
    const int bn   = blockIdx.x * 16;

    // --- staging assignment ---
    // A: thread covers slot als (0..15) of rows arg*8+i, i=0..7.
    //    global: coalesced 256B runs (16 consecutive lanes, same row).
    //    LDS: row r=arg*8+i -> off r*128 + ((als ^ i) << 3)   [r&7 == i]
    const int als = tid & 15;
    const int arg = tid >> 4;        // 0..15
    // B: thread covers row brow (0..15), slot bls (0..15).
    const int brow = tid >> 4;
    const int bls  = tid & 15;

    const unsigned short* gA = A + als * 8;                       // + r*lda + t*128
    const unsigned short* gB = BT + (size_t)(bn + brow) * K + bls * 8;  // + t*128

    floatx4 acc0 = {0.f, 0.f, 0.f, 0.f};
    floatx4 acc1 = {0.f, 0.f, 0.f, 0.f};

    const int nch = K >> 7;

    uint4 ar[8];
    uint4 br;

    // prologue: load + write chunk 0 into buffer 0
#pragma unroll
    for (int i = 0; i < 8; ++i)
        ar[i] = *reinterpret_cast<const uint4*>(gA + (size_t)(arg * 8 + i) * lda);
    br = *reinterpret_cast<const uint4*>(gB);
#pragma unroll
    for (int i = 0; i < 8; ++i)
        *reinterpret_cast<uint4*>(&lds[(arg * 8 + i) * 128 + ((als ^ i) << 3)]) = ar[i];
    *reinterpret_cast<uint4*>(&lds[16384 + brow * 128 + ((bls ^ (brow & 7)) << 3)]) = br;
    __syncthreads();

    const int ra0 = (32 * w + lo) * 128;   // A LDS row base (shorts) for a0
    const int rb0 = 16384 + lo * 128;      // B LDS row base

    for (int t = 0; t < nch; ++t) {
        // issue next chunk's global loads early (latency hides under MFMA)
        if (t + 1 < nch) {
            const unsigned short* ga = gA + (size_t)(t + 1) * 128;
            const unsigned short* gb = gB + (size_t)(t + 1) * 128;
#pragma unroll
            for (int i = 0; i < 8; ++i)
                ar[i] = *reinterpret_cast<const uint4*>(ga + (size_t)(arg * 8 + i) * lda);
            br = *reinterpret_cast<const uint4*>(gb);
        }

        const unsigned short* Lb = lds + (t & 1) * 18432;
#pragma unroll
        for (int u = 0; u < 4; ++u) {
            const int ph = ((hi + 4 * u) ^ fq) << 3;   // swizzled slot offset
            halfx8 a0 = *reinterpret_cast<const halfx8*>(Lb + ra0 + ph);
            halfx8 a1 = *reinterpret_cast<const halfx8*>(Lb + ra0 + 2048 + ph);
            halfx8 b  = *reinterpret_cast<const halfx8*>(Lb + rb0 + ph);
            acc0 = __builtin_amdgcn_mfma_f32_16x16x32_f16(a0, b, acc0, 0, 0, 0);
            acc1 = __builtin_amdgcn_mfma_f32_16x16x32_f16(a1, b, acc1, 0, 0, 0);
        }

        // write next chunk into the other buffer (read last iteration;
        // the end-of-iteration barrier ordered those reads before us)
        if (t + 1 < nch) {
            unsigned short* Ln = lds + ((t + 1) & 1) * 18432;
#pragma unroll
            for (int i = 0; i < 8; ++i)
                *reinterpret_cast<uint4*>(&Ln[(arg * 8 + i) * 128 + ((als ^ i) << 3)]) = ar[i];
            *reinterpret_cast<uint4*>(&Ln[16384 + brow * 128 + ((bls ^ (brow & 7)) << 3)]) = br;
        }
        __syncthreads();
    }

    // epilogue: C/D layout col = lane&15, row = (lane>>4)*4 + reg
    const int col = bn + lo;
#pragma unroll
    for (int fn = 0; fn < 2; ++fn) {
        floatx4 a = (fn == 0) ? acc0 : acc1;
        const int row_base = w * 32 + fn * 16 + hi * 4;
#pragma unroll
        for (int rr = 0; rr < 4; ++rr) {
            int row = row_base + rr;
            float v = a[rr];
            if (EPI == 0) {
                int sidx = (row < 64) ? sF : sB;
                v += biasp[col] + ts[2 * sidx] * Wtn[col] + ts[2 * sidx + 1] * Wtn[HH + col];
                v = fmaxf(v, 0.f);
                ((unsigned short*)Cout)[(size_t)row * ldc + col] = f2h_bits(v);
            } else if (EPI == 1) {
                v = fmaxf(v + biasp[col], 0.f);
                ((unsigned short*)Cout)[(size_t)row * ldc + col] = f2h_bits(v);
            } else {
                ((float*)Cout)[(size_t)row * ldc + col] = v;
            }
        }
    }
}

// ---------------------------------------------------------------------------
// Fallback GEMM (round-1 path, reads fp32 weights directly). BM=32,BN=64,BK=32.
// ---------------------------------------------------------------------------
template <int BMODE, int EPI>
__global__ __launch_bounds__(256) void gemm_kernel(
        const unsigned short* __restrict__ A, int lda, int K,
        const float* __restrict__ Bp0, const float* __restrict__ Bp1,
        const float* __restrict__ Bp2, int ldb,
        void* __restrict__ Cout, int ldc,
        const float* __restrict__ biasp, const float* __restrict__ Wtn,
        const float* __restrict__ ts, int sF, int sB) {
    __shared__ unsigned short As[32][40];
    __shared__ unsigned short Bs[64][40];

    const int tid  = threadIdx.x;
    const int wave = tid >> 6;
    const int lane = tid & 63;
    const int fl   = lane & 15;
    const int qd   = lane >> 4;
    const int bm   = blockIdx.y * 32;
    const int bn   = blockIdx.x * 64;
    const int wm   = (wave >> 1) * 16;
    const int wn   = (wave & 1) * 32;

    const int ar = tid >> 3;
    const int ak = (tid & 7) * 4;
    const int kloc = wave * 8;
    const int bnl  = lane;

    floatx4 acc0 = {0.f, 0.f, 0.f, 0.f};
    floatx4 acc1 = {0.f, 0.f, 0.f, 0.f};

    for (int k0 = 0; k0 < K; k0 += 32) {
        *reinterpret_cast<uint2*>(&As[ar][ak]) =
            *reinterpret_cast<const uint2*>(A + (size_t)(bm + ar) * lda + k0 + ak);

        float fv[8];
        if (BMODE == 0) {
            int kk = k0 + kloc;
            const float* base = (kk < 2048) ? (Bp0 + (size_t)kk * ldb)
                                            : (Bp1 + (size_t)(kk - 2048) * ldb);
            base += bn + bnl;
#pragma unroll
            for (int j = 0; j < 8; ++j) fv[j] = base[(size_t)j * ldb];
        } else if (BMODE == 1) {
            const float* base = Bp0 + (size_t)(k0 + kloc) * ldb + bn + bnl;
#pragma unroll
            for (int j = 0; j < 8; ++j) fv[j] = base[(size_t)j * ldb];
        } else {
            int third = bn >> 11;
            const float* Bsel = (third == 0) ? Bp0 : ((third == 1) ? Bp1 : Bp2);
            const float* base = Bsel + (size_t)(k0 + kloc) * ldb + (bn - (third << 11)) + bnl;
#pragma unroll
            for (int j = 0; j < 8; ++j) fv[j] = base[(size_t)j * ldb];
        }
        union { unsigned short us[8]; uint4 v; } pk;
#pragma unroll
        for (int j = 0; j < 8; ++j) pk.us[j] = f2h_bits(fv[j]);
        *reinterpret_cast<uint4*>(&Bs[bnl][kloc]) = pk.v;

        __syncthreads();

        halfx8 afr = *reinterpret_cast<const halfx8*>(&As[wm + fl][qd * 8]);
        halfx8 bf0 = *reinterpret_cast<const halfx8*>(&Bs[wn + fl][qd * 8]);
        halfx8 bf1 = *reinterpret_cast<const halfx8*>(&Bs[wn + 16 + fl][qd * 8]);
        acc0 = __builtin_amdgcn_mfma_f32_16x16x32_f16(afr, bf0, acc0, 0, 0, 0);
        acc1 = __builtin_amdgcn_mfma_f32_16x16x32_f16(afr, bf1, acc1, 0, 0, 0);

        __syncthreads();
    }

    const int row0 = bm + wm + qd * 4;
#pragma unroll
    for (int fn = 0; fn < 2; ++fn) {
        floatx4 a = (fn == 0) ? acc0 : acc1;
        int col = bn + wn + fn * 16 + fl;
#pragma unroll
        for (int rr = 0; rr < 4; ++rr) {
            int row = row0 + rr;
            float v = a[rr];
            if (EPI == 0) {
                int sidx = (row < 64) ? sF : sB;
                v += biasp[col] + ts[2 * sidx] * Wtn[col] + ts[2 * sidx + 1] * Wtn[HH + col];
                v = fmaxf(v, 0.f);
                ((unsigned short*)Cout)[(size_t)row * ldc + col] = f2h_bits(v);
            } else if (EPI == 1) {
                v = fmaxf(v + biasp[col], 0.f);
                ((unsigned short*)Cout)[(size_t)row * ldc + col] = f2h_bits(v);
            } else {
                ((float*)Cout)[(size_t)row * ldc + col] = v;
            }
        }
    }
}

// ---------------------------------------------------------------------------
// block reduce + one atomic per block
// ---------------------------------------------------------------------------
__device__ __forceinline__ void block_reduce_atomic(float v, float* dst) {
    for (int off = 32; off; off >>= 1) v += __shfl_down(v, off, 64);
    __shared__ float red[4];
    if ((threadIdx.x & 63) == 0) red[threadIdx.x >> 6] = v;
    __syncthreads();
    if (threadIdx.x == 0) atomicAdd(dst, red[0] + red[1] + red[2] + red[3]);
}

// ---------------------------------------------------------------------------
// fused update kernels: apply state update AND write next sub-step's A-operand
// grid: (DD/256, BBr)
// ---------------------------------------------------------------------------
__global__ void update_mom_kernel(const float* __restrict__ pos, float* __restrict__ mom,
                                  float* __restrict__ sld, const float* __restrict__ STQ,
                                  const float* __restrict__ bs, const float* __restrict__ cs,
                                  const float* __restrict__ btr, const float* __restrict__ bq,
                                  const float* __restrict__ cq, const float* __restrict__ eps,
                                  const float* __restrict__ masks, int sF, int sB,
                                  int writeNext, unsigned short* __restrict__ Abuf) {
    int r = blockIdx.y;
    int d = blockIdx.x * 256 + threadIdx.x;
    float e = eps[0];
    size_t ro = (size_t)r * 6144;
    float S = tanhf(STQ[ro + d] + bs[d]) * expf(cs[d]);
    float T = STQ[ro + 2048 + d] + btr[d];
    float Q = tanhf(STQ[ro + 4096 + d] + bq[d]) * expf(cq[d]);
    size_t idx = (size_t)r * 2048 + d;
    float p = pos[idx], v = mom[idx];
    float g = sinf(p);
    float tr = e * Q, sc;
    if (r < 64) { sc = 0.5f * e * S;  v = v * expf(sc) - 0.5f * e * (expf(tr) * g - T); }
    else        { sc = -0.5f * e * S; v = expf(sc) * (v + 0.5f * e * (expf(tr) * g - T)); }
    mom[idx] = v;
    if (writeNext) {   // next sub is pos-type with sub==2
        float m2 = (r < 64) ? masks[sF * 2048 + d] : 1.f - masks[sB * 2048 + d];
        Abuf[(r << 12) + d]        = f2h_bits(v);
        Abuf[(r << 12) + 2048 + d] = f2h_bits(m2 * p);
    }
    block_reduce_atomic(sc, sld + r);
}

__global__ void update_pos_kernel(float* __restrict__ pos, const float* __restrict__ mom,
                                  float* __restrict__ sld, const float* __restrict__ STQ,
                                  const float* __restrict__ bs, const float* __restrict__ cs,
                                  const float* __restrict__ btr, const float* __restrict__ bq,
                                  const float* __restrict__ cq, const float* __restrict__ eps,
                                  const float* __restrict__ masks, int sF, int sB, int sub,
                                  unsigned short* __restrict__ Abuf) {
    int r = blockIdx.y;
    int d = blockIdx.x * 256 + threadIdx.x;
    float e = eps[0];
    size_t ro = (size_t)r * 6144;
    float S = tanhf(STQ[ro + d] + bs[d]) * expf(cs[d]);
    float T = STQ[ro + 2048 + d] + btr[d];
    float Q = tanhf(STQ[ro + 4096 + d] + bq[d]) * expf(cq[d]);
    size_t idx = (size_t)r * 2048 + d;
    float p = pos[idx], v = mom[idx];
    float sc = e * S, tr = e * Q;
    float mf = masks[sF * 2048 + d], mb = masks[sB * 2048 + d];
    float pn, ld;
    if (r < 64) {
        float m  = (sub == 2) ? mf : 1.f - mf;
        float mi = 1.f - m;
        pn = m * p + mi * (p * expf(sc) + e * (expf(tr) * v + T));
        ld = mi * sc;
    } else {
        float m  = (sub == 2) ? 1.f - mb : mb;
        float mi = 1.f - m;
        pn = m * p + mi * expf(sc) * (p - e * (expf(tr) * v + T));
        ld = mi * sc;
    }
    pos[idx] = pn;
    if (sub == 2) {   // next sub is pos-type with sub==3
        float m3 = (r < 64) ? 1.f - mf : mb;
        Abuf[(r << 12) + d]        = f2h_bits(v);
        Abuf[(r << 12) + 2048 + d] = f2h_bits(m3 * pn);
    } else {          // next sub is mom-type
        Abuf[(r << 12) + d]        = f2h_bits(pn);
        Abuf[(r << 12) + 2048 + d] = f2h_bits(sinf(pn));
    }
    block_reduce_atomic(ld, sld + r);
}

// ---------------------------------------------------------------------------
// accept prob per row (128 blocks)
// ---------------------------------------------------------------------------
__global__ void accept_kernel(const float* __restrict__ position,
                              const float* __restrict__ momf, const float* __restrict__ momb,
                              const float* __restrict__ pos, const float* __restrict__ mom,
                              const float* __restrict__ sld, float* __restrict__ ap_all) {
    int r = blockIdx.x;
    int rb = r & 63;
    const float* m0 = (r < 64) ? (momf + (size_t)rb * 2048) : (momb + (size_t)rb * 2048);
    float s = 0.f;
    for (int d = threadIdx.x; d < 2048; d += 256) {
        float x0 = position[rb * 2048 + d];
        float v0 = m0[d];
        float x1 = pos[(size_t)r * 2048 + d];
        float v1 = mom[(size_t)r * 2048 + d];
        s += (cosf(x1) - cosf(x0)) + 0.5f * (v0 * v0 - v1 * v1);
    }
    for (int off = 32; off; off >>= 1) s += __shfl_down(s, off, 64);
    __shared__ float red[4];
    if ((threadIdx.x & 63) == 0) red[threadIdx.x >> 6] = s;
    __syncthreads();
    if (threadIdx.x == 0) {
        float dd = red[0] + red[1] + red[2] + red[3] + sld[r];
        float p = isnan(dd) ? 0.f : expf(dd < 0.f ? dd : 0.f);
        if (!isfinite(p)) p = 0.f;
        ap_all[r] = p;
    }
}

// ---------------------------------------------------------------------------
// combine -> outputs: [position_post | momentum_post | ap | position_out]
// ---------------------------------------------------------------------------
__global__ void combine_kernel(const float* __restrict__ position,
                               const float* __restrict__ u_dir, const float* __restrict__ u_accept,
                               const float* __restrict__ pos, const float* __restrict__ mom,
                               const float* __restrict__ ap_all, float* __restrict__ out) {
    int idx = blockIdx.x * 256 + threadIdx.x;  // over BD*DD
    int b = idx >> 11, d = idx & 2047;
    float fm = (u_dir[b] > 0.5f) ? 1.f : 0.f;
    float pf = pos[(size_t)b * 2048 + d],       pb = pos[(size_t)(64 + b) * 2048 + d];
    float mf = mom[(size_t)b * 2048 + d],       mb = mom[(size_t)(64 + b) * 2048 + d];
    float ppost = fm * pf + (1.f - fm) * pb;
    float mpost = fm * mf + (1.f - fm) * mb;
    float ap = fm * ap_all[b] + (1.f - fm) * ap_all[64 + b];
    float am = (ap > u_accept[b]) ? 1.f : 0.f;
    out[idx] = ppost;
    out[131072 + idx] = mpost;
    if (d == 0) out[262144 + b] = ap;
    out[262208 + idx] = am * ppost + (1.f - am) * position[idx];
}

// ---------------------------------------------------------------------------
extern "C" void kernel_launch(void* const* d_in, const int* in_sizes, int n_in,
                              void* d_out, int out_size, void* d_ws, size_t ws_size,
                              hipStream_t stream) {
    const float* position   = (const float*)d_in[0];
    const float* momentum_f = (const float*)d_in[1];
    const float* momentum_b = (const float*)d_in[2];
    const float* u_dir      = (const float*)d_in[3];
    const float* u_accept   = (const float*)d_in[4];
    const float* eps        = (const float*)d_in[5];
    const float* masks      = (const float*)d_in[6];
    const float* ts         = (const float*)d_in[7];
    const float* W1         = (const float*)d_in[8];
    const float* W2         = (const float*)d_in[9];
    const float* Wt         = (const float*)d_in[10];
    const float* b1         = (const float*)d_in[11];
    const float* Wh         = (const float*)d_in[12];
    const float* bh         = (const float*)d_in[13];
    const float* Ws         = (const float*)d_in[14];
    const float* bs         = (const float*)d_in[15];
    const float* cs         = (const float*)d_in[16];
    const float* Wtr        = (const float*)d_in[17];
    const float* btr        = (const float*)d_in[18];
    const float* Wq         = (const float*)d_in[19];
    const float* bq         = (const float*)d_in[20];
    const float* cq         = (const float*)d_in[21];
    float* out = (float*)d_out;

    // ---- workspace carve ----
    float* pos    = (float*)d_ws;               // 128*2048
    float* mom    = pos + BBr * DD;
    float* sld    = mom + BBr * DD;             // 128
    float* ap_all = sld + BBr;                  // 128
    float* STQ    = ap_all + BBr;               // 128*6144
    unsigned short* Abuf = (unsigned short*)(STQ + BBr * 3 * DD);  // 128*4096
    unsigned short* h1   = Abuf + (size_t)BBr * 2 * DD;            // 128*4096
    unsigned short* h2   = h1 + (size_t)BBr * HH;                  // 128*4096
    unsigned short* BTw  = h2 + (size_t)BBr * HH;                  // weights f16

    const size_t BT1sz = (size_t)HH * 2 * DD;   // 4096*4096
    const size_t BThsz = (size_t)HH * HH;       // 4096*4096
    const size_t BT3sz = (size_t)3 * DD * HH;   // 6144*4096
    const size_t perNet = BT1sz + BThsz + BT3sz;
    unsigned short* BT1[2] = { BTw,                 BTw + perNet };
    unsigned short* BTh[2] = { BTw + BT1sz,         BTw + perNet + BT1sz };
    unsigned short* BT3[2] = { BTw + BT1sz + BThsz, BTw + perNet + BT1sz + BThsz };

    const size_t NEED = (size_t)((char*)(BTw + 2 * perNet) - (char*)d_ws);
    const bool fast = (ws_size >= NEED);

    const size_t DH  = (size_t)DD * HH;
    const size_t HH2 = (size_t)HH * HH;

    init_kernel<<<BBr * DD / 256, 256, 0, stream>>>(position, momentum_f, momentum_b,
                                                    pos, mom, sld, Abuf);

    if (fast) {
        // weight conversion: fp32 KxN -> f16 NxK (transposed)
        for (int n = 0; n < 2; ++n) {
            // GEMM1: rows n (H), cols k = [W1 | W2]
            transpose_cvt_kernel<<<dim3(HH / 32, DD / 32), 256, 0, stream>>>(
                W1 + n * DH, HH, BT1[n], 2 * DD);
            transpose_cvt_kernel<<<dim3(HH / 32, DD / 32), 256, 0, stream>>>(
                W2 + n * DH, HH, BT1[n] + DD, 2 * DD);
            // GEMM2: Wh
            transpose_cvt_kernel<<<dim3(HH / 32, HH / 32), 256, 0, stream>>>(
                Wh + n * HH2, HH, BTh[n], HH);
            // GEMM3: rows n = [Ws-d | Wtr-d | Wq-d], cols k (H)
            transpose_cvt_kernel<<<dim3(DD / 32, HH / 32), 256, 0, stream>>>(
                Ws + n * DH, DD, BT3[n], HH);
            transpose_cvt_kernel<<<dim3(DD / 32, HH / 32), 256, 0, stream>>>(
                Wtr + n * DH, DD, BT3[n] + (size_t)DD * HH, HH);
            transpose_cvt_kernel<<<dim3(DD / 32, HH / 32), 256, 0, stream>>>(
                Wq + n * DH, DD, BT3[n] + (size_t)2 * DD * HH, HH);
        }
    }

    for (int i = 0; i < NSS; ++i) {
        int sF = i, sB = NSS - 1 - i;
        for (int subidx = 0; subidx < 4; ++subidx) {
            bool isMom = (subidx == 0 || subidx == 3);
            int n = isMom ? 1 : 0;            // MOM net = 1, POS net = 0
            int sub = (subidx == 1) ? 2 : 3;  // pos sub-update flavor

            if (fast) {
                gemm_lds_kernel<0><<<HH / 16, 256, 0, stream>>>(
                    Abuf, 2 * DD, 2 * DD, BT1[n], h1, HH,
                    b1 + n * HH, Wt + n * 2 * HH, ts, sF, sB);
                gemm_lds_kernel<1><<<HH / 16, 256, 0, stream>>>(
                    h1, HH, HH, BTh[n], h2, HH,
                    bh + n * HH, nullptr, ts, sF, sB);
                gemm_lds_kernel<2><<<3 * DD / 16, 256, 0, stream>>>(
                    h2, HH, HH, BT3[n], STQ, 3 * DD,
                    nullptr, nullptr, ts, sF, sB);
            } else {
                gemm_kernel<0, 0><<<dim3(HH / 64, 4), 256, 0, stream>>>(
                    Abuf, 2 * DD, 2 * DD,
                    W1 + n * DH, W2 + n * DH, nullptr, HH, h1, HH,
                    b1 + n * HH, Wt + n * 2 * HH, ts, sF, sB);
                gemm_kernel<1, 1><<<dim3(HH / 64, 4), 256, 0, stream>>>(
                    h1, HH, HH, Wh + n * HH2, nullptr, nullptr, HH, h2, HH,
                    bh + n * HH, nullptr, ts, sF, sB);
                gemm_kernel<2, 2><<<dim3(3 * DD / 64, 4), 256, 0, stream>>>(
                    h2, HH, HH, Ws + n * DH, Wtr + n * DH, Wq + n * DH, DD, STQ, 3 * DD,
                    nullptr, nullptr, ts, sF, sB);
            }

            if (isMom)
                update_mom_kernel<<<dim3(DD / 256, BBr), 256, 0, stream>>>(
                    pos, mom, sld, STQ, bs + DD, cs + DD, btr + DD, bq + DD, cq + DD,
                    eps, masks, sF, sB, (subidx == 0) ? 1 : 0, Abuf);
            else
                update_pos_kernel<<<dim3(DD / 256, BBr), 256, 0, stream>>>(
                    pos, mom, sld, STQ, bs, cs, btr, bq, cq, eps, masks, sF, sB, sub, Abuf);
        }
    }

    accept_kernel<<<BBr, 256, 0, stream>>>(position, momentum_f, momentum_b,
                                           pos, mom, sld, ap_all);
    combine_kernel<<<BD * DD / 256, 256, 0, stream>>>(position, u_dir, u_accept,
                                                      pos, mom, ap_all, out);
}

// Round 5
// 18790.001 us; speedup vs baseline: 1.5994x; 1.5994x over previous
//
#include <hip/hip_runtime.h>

// Problem constants
#define BD   64      // batch per direction
#define DD   2048
#define HH   4096
#define NSS  25
#define BBr  128     // combined rows (fwd 0..63, bwd 64..127)

typedef _Float16 halfx8 __attribute__((ext_vector_type(8)));
typedef float    floatx4 __attribute__((ext_vector_type(4)));

__device__ __forceinline__ unsigned short f2h_bits(float x) {
    union { _Float16 h; unsigned short u; } c;
    c.h = (_Float16)x;
    return c.u;
}

// ---------------------------------------------------------------------------
// init: state + first A-operand (mom-type: [pos | sin(pos)])
// ---------------------------------------------------------------------------
__global__ void init_kernel(const float* __restrict__ position,
                            const float* __restrict__ momf,
                            const float* __restrict__ momb,
                            float* __restrict__ pos, float* __restrict__ mom,
                            float* __restrict__ sld,
                            unsigned short* __restrict__ Abuf) {
    int idx = blockIdx.x * 256 + threadIdx.x;   // over BBr*DD
    int r = idx >> 11, d = idx & 2047;
    float p = position[((r & 63) << 11) + d];
    pos[idx] = p;
    mom[idx] = (r < 64) ? momf[(r << 11) + d] : momb[((r - 64) << 11) + d];
    Abuf[(r << 12) + d]        = f2h_bits(p);
    Abuf[(r << 12) + 2048 + d] = f2h_bits(sinf(p));
    if (idx < BBr) sld[idx] = 0.f;
}

// ---------------------------------------------------------------------------
// Weight conversion: fp32 (rows x cols, ldi) -> f16 transposed (cols x rows, ldo)
// 32x32 LDS tile. grid: (cols/32, rows/32), 256 threads.
// ---------------------------------------------------------------------------
__global__ __launch_bounds__(256) void transpose_cvt_kernel(
        const float* __restrict__ src, int ldi,
        unsigned short* __restrict__ dst, int ldo) {
    __shared__ float tile[32][33];
    const int rb = blockIdx.y * 32;   // src row base
    const int cb = blockIdx.x * 32;   // src col base
    const int t  = threadIdx.x;
    const int r  = t >> 3;
    const int c4 = (t & 7) * 4;
    float4 v = *reinterpret_cast<const float4*>(src + (size_t)(rb + r) * ldi + cb + c4);
    tile[r][c4 + 0] = v.x; tile[r][c4 + 1] = v.y;
    tile[r][c4 + 2] = v.z; tile[r][c4 + 3] = v.w;
    __syncthreads();
    union { unsigned short us[4]; uint2 v; } pk;
#pragma unroll
    for (int j = 0; j < 4; ++j) pk.us[j] = f2h_bits(tile[c4 + j][r]);
    *reinterpret_cast<uint2*>(dst + (size_t)(cb + r) * ldo + rb + c4) = pk.v;
}

// ---------------------------------------------------------------------------
// Split-K direct-load GEMM: C(128 x N) = A(128 x K f16) @ BT(N x K f16)^T
// The harness-verified round-0 wave body (direct global 16B loads -> MFMA,
// no LDS staging) with intra-block split-K for occupancy:
//   block = KS*256 threads = KS*4 waves; wave (kq, mw) computes rows
//   [32*mw, 32*mw+32) over K-slice kq of length K/KS; partials reduced in
//   LDS at the end, epilogue by the kq==0 waves (identical to baseline).
// Rationale (round-3 post-mortem): grid is fixed at N/16 = 256 blocks =
// 1 block/CU; with 4 waves that is 1 wave/SIMD and the ~500-900cy L2/L3
// load latency is fully exposed (~60us/GEMM vs ~9us L2-BW floor).
// KS=4 (1024 thr) -> 4 waves/SIMD; KS=2 (512 thr) for N=6144 (384 blocks,
// 2 blocks/CU co-resident -> also 4 waves/SIMD).
// __launch_bounds__(KS*256, 4) caps VGPR at 128 (body ~80, no spill).
// EPI 0: relu(+b1 + t@Wt) -> f16 ; EPI 1: relu(+bh) -> f16 ; EPI 2: raw fp32
// ---------------------------------------------------------------------------
template <int EPI, int KS>
__global__ __launch_bounds__(KS * 256, 4) void gemm_bt_kernel(
        const unsigned short* __restrict__ A, int lda, int K,
        const unsigned short* __restrict__ BT,
        void* __restrict__ Cout, int ldc,
        const float* __restrict__ biasp, const float* __restrict__ Wtn,
        const float* __restrict__ ts, int sF, int sB) {
    const int tid  = threadIdx.x;
    const int lane = tid & 63;
    const int mw   = (tid >> 6) & 3;   // M-wave position 0..3
    const int kq   = tid >> 8;         // K-slice 0..KS-1
    const int fl   = lane & 15;
    const int qd   = lane >> 4;
    const int bn   = blockIdx.x * 16;

    const int Kq = K / KS;
    const unsigned short* pa0 = A + (size_t)(mw * 32 + fl) * lda + kq * Kq + qd * 8;
    const unsigned short* pa1 = pa0 + (size_t)16 * lda;
    const unsigned short* pb  = BT + (size_t)(bn + fl) * K + kq * Kq + qd * 8;

    floatx4 acc0 = {0.f, 0.f, 0.f, 0.f};
    floatx4 acc1 = {0.f, 0.f, 0.f, 0.f};

    for (int k0 = 0; k0 < Kq; k0 += 128) {
#pragma unroll
        for (int u = 0; u < 4; ++u) {
            halfx8 a0 = *reinterpret_cast<const halfx8*>(pa0 + u * 32);
            halfx8 a1 = *reinterpret_cast<const halfx8*>(pa1 + u * 32);
            halfx8 b  = *reinterpret_cast<const halfx8*>(pb  + u * 32);
            acc0 = __builtin_amdgcn_mfma_f32_16x16x32_f16(a0, b, acc0, 0, 0, 0);
            acc1 = __builtin_amdgcn_mfma_f32_16x16x32_f16(a1, b, acc1, 0, 0, 0);
        }
        pa0 += 128; pa1 += 128; pb += 128;
    }

    // cross-K-slice reduction (one barrier; fp reorder only vs baseline)
    __shared__ float red[(KS - 1) * 4][64][8];
    if (kq > 0) {
        float* p = &red[(kq - 1) * 4 + mw][lane][0];
#pragma unroll
        for (int j = 0; j < 4; ++j) { p[j] = acc0[j]; p[j + 4] = acc1[j]; }
    }
    __syncthreads();
    if (kq != 0) return;
#pragma unroll
    for (int q = 0; q < KS - 1; ++q) {
        const float* p = &red[q * 4 + mw][lane][0];
#pragma unroll
        for (int j = 0; j < 4; ++j) { acc0[j] += p[j]; acc1[j] += p[j + 4]; }
    }

    // epilogue: C/D layout col = lane&15, row = (lane>>4)*4 + reg
    const int col = bn + fl;
#pragma unroll
    for (int fn = 0; fn < 2; ++fn) {
        floatx4 a = (fn == 0) ? acc0 : acc1;
        const int row_base = mw * 32 + fn * 16 + qd * 4;
#pragma unroll
        for (int rr = 0; rr < 4; ++rr) {
            int row = row_base + rr;
            float v = a[rr];
            if (EPI == 0) {
                int sidx = (row < 64) ? sF : sB;
                v += biasp[col] + ts[2 * sidx] * Wtn[col] + ts[2 * sidx + 1] * Wtn[HH + col];
                v = fmaxf(v, 0.f);
                ((unsigned short*)Cout)[(size_t)row * ldc + col] = f2h_bits(v);
            } else if (EPI == 1) {
                v = fmaxf(v + biasp[col], 0.f);
                ((unsigned short*)Cout)[(size_t)row * ldc + col] = f2h_bits(v);
            } else {
                ((float*)Cout)[(size_t)row * ldc + col] = v;
            }
        }
    }
}

// ---------------------------------------------------------------------------
// Fallback GEMM (reads fp32 weights directly). BM=32,BN=64,BK=32.
// ---------------------------------------------------------------------------
template <int BMODE, int EPI>
__global__ __launch_bounds__(256) void gemm_kernel(
        const unsigned short* __restrict__ A, int lda, int K,
        const float* __restrict__ Bp0, const float* __restrict__ Bp1,
        const float* __restrict__ Bp2, int ldb,
        void* __restrict__ Cout, int ldc,
        const float* __restrict__ biasp, const float* __restrict__ Wtn,
        const float* __restrict__ ts, int sF, int sB) {
    __shared__ unsigned short As[32][40];
    __shared__ unsigned short Bs[64][40];

    const int tid  = threadIdx.x;
    const int wave = tid >> 6;
    const int lane = tid & 63;
    const int fl   = lane & 15;
    const int qd   = lane >> 4;
    const int bm   = blockIdx.y * 32;
    const int bn   = blockIdx.x * 64;
    const int wm   = (wave >> 1) * 16;
    const int wn   = (wave & 1) * 32;

    const int ar = tid >> 3;
    const int ak = (tid & 7) * 4;
    const int kloc = wave * 8;
    const int bnl  = lane;

    floatx4 acc0 = {0.f, 0.f, 0.f, 0.f};
    floatx4 acc1 = {0.f, 0.f, 0.f, 0.f};

    for (int k0 = 0; k0 < K; k0 += 32) {
        *reinterpret_cast<uint2*>(&As[ar][ak]) =
            *reinterpret_cast<const uint2*>(A + (size_t)(bm + ar) * lda + k0 + ak);

        float fv[8];
        if (BMODE == 0) {
            int kk = k0 + kloc;
            const float* base = (kk < 2048) ? (Bp0 + (size_t)kk * ldb)
                                            : (Bp1 + (size_t)(kk - 2048) * ldb);
            base += bn + bnl;
#pragma unroll
            for (int j = 0; j < 8; ++j) fv[j] = base[(size_t)j * ldb];
        } else if (BMODE == 1) {
            const float* base = Bp0 + (size_t)(k0 + kloc) * ldb + bn + bnl;
#pragma unroll
            for (int j = 0; j < 8; ++j) fv[j] = base[(size_t)j * ldb];
        } else {
            int third = bn >> 11;
            const float* Bsel = (third == 0) ? Bp0 : ((third == 1) ? Bp1 : Bp2);
            const float* base = Bsel + (size_t)(k0 + kloc) * ldb + (bn - (third << 11)) + bnl;
#pragma unroll
            for (int j = 0; j < 8; ++j) fv[j] = base[(size_t)j * ldb];
        }
        union { unsigned short us[8]; uint4 v; } pk;
#pragma unroll
        for (int j = 0; j < 8; ++j) pk.us[j] = f2h_bits(fv[j]);
        *reinterpret_cast<uint4*>(&Bs[bnl][kloc]) = pk.v;

        __syncthreads();

        halfx8 afr = *reinterpret_cast<const halfx8*>(&As[wm + fl][qd * 8]);
        halfx8 bf0 = *reinterpret_cast<const halfx8*>(&Bs[wn + fl][qd * 8]);
        halfx8 bf1 = *reinterpret_cast<const halfx8*>(&Bs[wn + 16 + fl][qd * 8]);
        acc0 = __builtin_amdgcn_mfma_f32_16x16x32_f16(afr, bf0, acc0, 0, 0, 0);
        acc1 = __builtin_amdgcn_mfma_f32_16x16x32_f16(afr, bf1, acc1, 0, 0, 0);

        __syncthreads();
    }

    const int row0 = bm + wm + qd * 4;
#pragma unroll
    for (int fn = 0; fn < 2; ++fn) {
        floatx4 a = (fn == 0) ? acc0 : acc1;
        int col = bn + wn + fn * 16 + fl;
#pragma unroll
        for (int rr = 0; rr < 4; ++rr) {
            int row = row0 + rr;
            float v = a[rr];
            if (EPI == 0) {
                int sidx = (row < 64) ? sF : sB;
                v += biasp[col] + ts[2 * sidx] * Wtn[col] + ts[2 * sidx + 1] * Wtn[HH + col];
                v = fmaxf(v, 0.f);
                ((unsigned short*)Cout)[(size_t)row * ldc + col] = f2h_bits(v);
            } else if (EPI == 1) {
                v = fmaxf(v + biasp[col], 0.f);
                ((unsigned short*)Cout)[(size_t)row * ldc + col] = f2h_bits(v);
            } else {
                ((float*)Cout)[(size_t)row * ldc + col] = v;
            }
        }
    }
}

// ---------------------------------------------------------------------------
// block reduce + one atomic per block
// ---------------------------------------------------------------------------
__device__ __forceinline__ void block_reduce_atomic(float v, float* dst) {
    for (int off = 32; off; off >>= 1) v += __shfl_down(v, off, 64);
    __shared__ float red[4];
    if ((threadIdx.x & 63) == 0) red[threadIdx.x >> 6] = v;
    __syncthreads();
    if (threadIdx.x == 0) atomicAdd(dst, red[0] + red[1] + red[2] + red[3]);
}

// ---------------------------------------------------------------------------
// fused update kernels: apply state update AND write next sub-step's A-operand
// grid: (DD/256, BBr)
// ---------------------------------------------------------------------------
__global__ void update_mom_kernel(const float* __restrict__ pos, float* __restrict__ mom,
                                  float* __restrict__ sld, const float* __restrict__ STQ,
                                  const float* __restrict__ bs, const float* __restrict__ cs,
                                  const float* __restrict__ btr, const float* __restrict__ bq,
                                  const float* __restrict__ cq, const float* __restrict__ eps,
                                  const float* __restrict__ masks, int sF, int sB,
                                  int writeNext, unsigned short* __restrict__ Abuf) {
    int r = blockIdx.y;
    int d = blockIdx.x * 256 + threadIdx.x;
    float e = eps[0];
    size_t ro = (size_t)r * 6144;
    float S = tanhf(STQ[ro + d] + bs[d]) * expf(cs[d]);
    float T = STQ[ro + 2048 + d] + btr[d];
    float Q = tanhf(STQ[ro + 4096 + d] + bq[d]) * expf(cq[d]);
    size_t idx = (size_t)r * 2048 + d;
    float p = pos[idx], v = mom[idx];
    float g = sinf(p);
    float tr = e * Q, sc;
    if (r < 64) { sc = 0.5f * e * S;  v = v * expf(sc) - 0.5f * e * (expf(tr) * g - T); }
    else        { sc = -0.5f * e * S; v = expf(sc) * (v + 0.5f * e * (expf(tr) * g - T)); }
    mom[idx] = v;
    if (writeNext) {   // next sub is pos-type with sub==2
        float m2 = (r < 64) ? masks[sF * 2048 + d] : 1.f - masks[sB * 2048 + d];
        Abuf[(r << 12) + d]        = f2h_bits(v);
        Abuf[(r << 12) + 2048 + d] = f2h_bits(m2 * p);
    }
    block_reduce_atomic(sc, sld + r);
}

__global__ void update_pos_kernel(float* __restrict__ pos, const float* __restrict__ mom,
                                  float* __restrict__ sld, const float* __restrict__ STQ,
                                  const float* __restrict__ bs, const float* __restrict__ cs,
                                  const float* __restrict__ btr, const float* __restrict__ bq,
                                  const float* __restrict__ cq, const float* __restrict__ eps,
                                  const float* __restrict__ masks, int sF, int sB, int sub,
                                  unsigned short* __restrict__ Abuf) {
    int r = blockIdx.y;
    int d = blockIdx.x * 256 + threadIdx.x;
    float e = eps[0];
    size_t ro = (size_t)r * 6144;
    float S = tanhf(STQ[ro + d] + bs[d]) * expf(cs[d]);
    float T = STQ[ro + 2048 + d] + btr[d];
    float Q = tanhf(STQ[ro + 4096 + d] + bq[d]) * expf(cq[d]);
    size_t idx = (size_t)r * 2048 + d;
    float p = pos[idx], v = mom[idx];
    float sc = e * S, tr = e * Q;
    float mf = masks[sF * 2048 + d], mb = masks[sB * 2048 + d];
    float pn, ld;
    if (r < 64) {
        float m  = (sub == 2) ? mf : 1.f - mf;
        float mi = 1.f - m;
        pn = m * p + mi * (p * expf(sc) + e * (expf(tr) * v + T));
        ld = mi * sc;
    } else {
        float m  = (sub == 2) ? 1.f - mb : mb;
        float mi = 1.f - m;
        pn = m * p + mi * expf(sc) * (p - e * (expf(tr) * v + T));
        ld = mi * sc;
    }
    pos[idx] = pn;
    if (sub == 2) {   // next sub is pos-type with sub==3
        float m3 = (r < 64) ? 1.f - mf : mb;
        Abuf[(r << 12) + d]        = f2h_bits(v);
        Abuf[(r << 12) + 2048 + d] = f2h_bits(m3 * pn);
    } else {          // next sub is mom-type
        Abuf[(r << 12) + d]        = f2h_bits(pn);
        Abuf[(r << 12) + 2048 + d] = f2h_bits(sinf(pn));
    }
    block_reduce_atomic(ld, sld + r);
}

// ---------------------------------------------------------------------------
// accept prob per row (128 blocks)
// ---------------------------------------------------------------------------
__global__ void accept_kernel(const float* __restrict__ position,
                              const float* __restrict__ momf, const float* __restrict__ momb,
                              const float* __restrict__ pos, const float* __restrict__ mom,
                              const float* __restrict__ sld, float* __restrict__ ap_all) {
    int r = blockIdx.x;
    int rb = r & 63;
    const float* m0 = (r < 64) ? (momf + (size_t)rb * 2048) : (momb + (size_t)rb * 2048);
    float s = 0.f;
    for (int d = threadIdx.x; d < 2048; d += 256) {
        float x0 = position[rb * 2048 + d];
        float v0 = m0[d];
        float x1 = pos[(size_t)r * 2048 + d];
        float v1 = mom[(size_t)r * 2048 + d];
        s += (cosf(x1) - cosf(x0)) + 0.5f * (v0 * v0 - v1 * v1);
    }
    for (int off = 32; off; off >>= 1) s += __shfl_down(s, off, 64);
    __shared__ float red[4];
    if ((threadIdx.x & 63) == 0) red[threadIdx.x >> 6] = s;
    __syncthreads();
    if (threadIdx.x == 0) {
        float dd = red[0] + red[1] + red[2] + red[3] + sld[r];
        float p = isnan(dd) ? 0.f : expf(dd < 0.f ? dd : 0.f);
        if (!isfinite(p)) p = 0.f;
        ap_all[r] = p;
    }
}

// ---------------------------------------------------------------------------
// combine -> outputs: [position_post | momentum_post | ap | position_out]
// ---------------------------------------------------------------------------
__global__ void combine_kernel(const float* __restrict__ position,
                               const float* __restrict__ u_dir, const float* __restrict__ u_accept,
                               const float* __restrict__ pos, const float* __restrict__ mom,
                               const float* __restrict__ ap_all, float* __restrict__ out) {
    int idx = blockIdx.x * 256 + threadIdx.x;  // over BD*DD
    int b = idx >> 11, d = idx & 2047;
    float fm = (u_dir[b] > 0.5f) ? 1.f : 0.f;
    float pf = pos[(size_t)b * 2048 + d],       pb = pos[(size_t)(64 + b) * 2048 + d];
    float mf = mom[(size_t)b * 2048 + d],       mb = mom[(size_t)(64 + b) * 2048 + d];
    float ppost = fm * pf + (1.f - fm) * pb;
    float mpost = fm * mf + (1.f - fm) * mb;
    float ap = fm * ap_all[b] + (1.f - fm) * ap_all[64 + b];
    float am = (ap > u_accept[b]) ? 1.f : 0.f;
    out[idx] = ppost;
    out[131072 + idx] = mpost;
    if (d == 0) out[262144 + b] = ap;
    out[262208 + idx] = am * ppost + (1.f - am) * position[idx];
}

// ---------------------------------------------------------------------------
extern "C" void kernel_launch(void* const* d_in, const int* in_sizes, int n_in,
                              void* d_out, int out_size, void* d_ws, size_t ws_size,
                              hipStream_t stream) {
    const float* position   = (const float*)d_in[0];
    const float* momentum_f = (const float*)d_in[1];
    const float* momentum_b = (const float*)d_in[2];
    const float* u_dir      = (const float*)d_in[3];
    const float* u_accept   = (const float*)d_in[4];
    const float* eps        = (const float*)d_in[5];
    const float* masks      = (const float*)d_in[6];
    const float* ts         = (const float*)d_in[7];
    const float* W1         = (const float*)d_in[8];
    const float* W2         = (const float*)d_in[9];
    const float* Wt         = (const float*)d_in[10];
    const float* b1         = (const float*)d_in[11];
    const float* Wh         = (const float*)d_in[12];
    const float* bh         = (const float*)d_in[13];
    const float* Ws         = (const float*)d_in[14];
    const float* bs         = (const float*)d_in[15];
    const float* cs         = (const float*)d_in[16];
    const float* Wtr        = (const float*)d_in[17];
    const float* btr        = (const float*)d_in[18];
    const float* Wq         = (const float*)d_in[19];
    const float* bq         = (const float*)d_in[20];
    const float* cq         = (const float*)d_in[21];
    float* out = (float*)d_out;

    // ---- workspace carve ----
    float* pos    = (float*)d_ws;               // 128*2048
    float* mom    = pos + BBr * DD;
    float* sld    = mom + BBr * DD;             // 128
    float* ap_all = sld + BBr;                  // 128
    float* STQ    = ap_all + BBr;               // 128*6144
    unsigned short* Abuf = (unsigned short*)(STQ + BBr * 3 * DD);  // 128*4096
    unsigned short* h1   = Abuf + (size_t)BBr * 2 * DD;            // 128*4096
    unsigned short* h2   = h1 + (size_t)BBr * HH;                  // 128*4096
    unsigned short* BTw  = h2 + (size_t)BBr * HH;                  // weights f16

    const size_t BT1sz = (size_t)HH * 2 * DD;   // 4096*4096
    const size_t BThsz = (size_t)HH * HH;       // 4096*4096
    const size_t BT3sz = (size_t)3 * DD * HH;   // 6144*4096
    const size_t perNet = BT1sz + BThsz + BT3sz;
    unsigned short* BT1[2] = { BTw,                 BTw + perNet };
    unsigned short* BTh[2] = { BTw + BT1sz,         BTw + perNet + BT1sz };
    unsigned short* BT3[2] = { BTw + BT1sz + BThsz, BTw + perNet + BT1sz + BThsz };

    const size_t NEED = (size_t)((char*)(BTw + 2 * perNet) - (char*)d_ws);
    const bool fast = (ws_size >= NEED);

    const size_t DH  = (size_t)DD * HH;
    const size_t HH2 = (size_t)HH * HH;

    init_kernel<<<BBr * DD / 256, 256, 0, stream>>>(position, momentum_f, momentum_b,
                                                    pos, mom, sld, Abuf);

    if (fast) {
        // weight conversion: fp32 KxN -> f16 NxK (transposed)
        for (int n = 0; n < 2; ++n) {
            // GEMM1: rows n (H), cols k = [W1 | W2]
            transpose_cvt_kernel<<<dim3(HH / 32, DD / 32), 256, 0, stream>>>(
                W1 + n * DH, HH, BT1[n], 2 * DD);
            transpose_cvt_kernel<<<dim3(HH / 32, DD / 32), 256, 0, stream>>>(
                W2 + n * DH, HH, BT1[n] + DD, 2 * DD);
            // GEMM2: Wh
            transpose_cvt_kernel<<<dim3(HH / 32, HH / 32), 256, 0, stream>>>(
                Wh + n * HH2, HH, BTh[n], HH);
            // GEMM3: rows n = [Ws-d | Wtr-d | Wq-d], cols k (H)
            transpose_cvt_kernel<<<dim3(DD / 32, HH / 32), 256, 0, stream>>>(
                Ws + n * DH, DD, BT3[n], HH);
            transpose_cvt_kernel<<<dim3(DD / 32, HH / 32), 256, 0, stream>>>(
                Wtr + n * DH, DD, BT3[n] + (size_t)DD * HH, HH);
            transpose_cvt_kernel<<<dim3(DD / 32, HH / 32), 256, 0, stream>>>(
                Wq + n * DH, DD, BT3[n] + (size_t)2 * DD * HH, HH);
        }
    }

    for (int i = 0; i < NSS; ++i) {
        int sF = i, sB = NSS - 1 - i;
        for (int subidx = 0; subidx < 4; ++subidx) {
            bool isMom = (subidx == 0 || subidx == 3);
            int n = isMom ? 1 : 0;            // MOM net = 1, POS net = 0
            int sub = (subidx == 1) ? 2 : 3;  // pos sub-update flavor

            if (fast) {
                gemm_bt_kernel<0, 4><<<HH / 16, 1024, 0, stream>>>(
                    Abuf, 2 * DD, 2 * DD, BT1[n], h1, HH,
                    b1 + n * HH, Wt + n * 2 * HH, ts, sF, sB);
                gemm_bt_kernel<1, 4><<<HH / 16, 1024, 0, stream>>>(
                    h1, HH, HH, BTh[n], h2, HH,
                    bh + n * HH, nullptr, ts, sF, sB);
                gemm_bt_kernel<2, 2><<<3 * DD / 16, 512, 0, stream>>>(
                    h2, HH, HH, BT3[n], STQ, 3 * DD,
                    nullptr, nullptr, ts, sF, sB);
            } else {
                gemm_kernel<0, 0><<<dim3(HH / 64, 4), 256, 0, stream>>>(
                    Abuf, 2 * DD, 2 * DD,
                    W1 + n * DH, W2 + n * DH, nullptr, HH, h1, HH,
                    b1 + n * HH, Wt + n * 2 * HH, ts, sF, sB);
                gemm_kernel<1, 1><<<dim3(HH / 64, 4), 256, 0, stream>>>(
                    h1, HH, HH, Wh + n * HH2, nullptr, nullptr, HH, h2, HH,
                    bh + n * HH, nullptr, ts, sF, sB);
                gemm_kernel<2, 2><<<dim3(3 * DD / 64, 4), 256, 0, stream>>>(
                    h2, HH, HH, Ws + n * DH, Wtr + n * DH, Wq + n * DH, DD, STQ, 3 * DD,
                    nullptr, nullptr, ts, sF, sB);
            }

            if (isMom)
                update_mom_kernel<<<dim3(DD / 256, BBr), 256, 0, stream>>>(
                    pos, mom, sld, STQ, bs + DD, cs + DD, btr + DD, bq + DD, cq + DD,
                    eps, masks, sF, sB, (subidx == 0) ? 1 : 0, Abuf);
            else
                update_pos_kernel<<<dim3(DD / 256, BBr), 256, 0, stream>>>(
                    pos, mom, sld, STQ, bs, cs, btr, bq, cq, eps, masks, sF, sB, sub, Abuf);
        }
    }

    accept_kernel<<<BBr, 256, 0, stream>>>(position, momentum_f, momentum_b,
                                           pos, mom, sld, ap_all);
    combine_kernel<<<BD * DD / 256, 256, 0, stream>>>(position, u_dir, u_accept,
                                                      pos, mom, ap_all, out);
}

// Round 6
// 18765.289 us; speedup vs baseline: 1.6015x; 1.0013x over previous
//
#include <hip/hip_runtime.h>
#include <hip/hip_cooperative_groups.h>

namespace cg = cooperative_groups;

// Problem constants
#define BD   64      // batch per direction
#define DD   2048
#define HH   4096
#define NSS  25
#define BBr  128     // combined rows (fwd 0..63, bwd 64..127)

typedef _Float16 halfx8 __attribute__((ext_vector_type(8)));
typedef float    floatx4 __attribute__((ext_vector_type(4)));

__device__ __forceinline__ unsigned short f2h_bits(float x) {
    union { _Float16 h; unsigned short u; } c;
    c.h = (_Float16)x;
    return c.u;
}

// ---------------------------------------------------------------------------
// init: state + first A-operand (mom-type: [pos | sin(pos)])
// ---------------------------------------------------------------------------
__global__ void init_kernel(const float* __restrict__ position,
                            const float* __restrict__ momf,
                            const float* __restrict__ momb,
                            float* __restrict__ pos, float* __restrict__ mom,
                            float* __restrict__ sld,
                            unsigned short* __restrict__ Abuf) {
    int idx = blockIdx.x * 256 + threadIdx.x;   // over BBr*DD
    int r = idx >> 11, d = idx & 2047;
    float p = position[((r & 63) << 11) + d];
    pos[idx] = p;
    mom[idx] = (r < 64) ? momf[(r << 11) + d] : momb[((r - 64) << 11) + d];
    Abuf[(r << 12) + d]        = f2h_bits(p);
    Abuf[(r << 12) + 2048 + d] = f2h_bits(sinf(p));
    if (idx < BBr) sld[idx] = 0.f;
}

// ---------------------------------------------------------------------------
// Weight conversion: fp32 (rows x cols, ldi) -> f16 transposed (cols x rows, ldo)
// ---------------------------------------------------------------------------
__global__ __launch_bounds__(256) void transpose_cvt_kernel(
        const float* __restrict__ src, int ldi,
        unsigned short* __restrict__ dst, int ldo) {
    __shared__ float tile[32][33];
    const int rb = blockIdx.y * 32;   // src row base
    const int cb = blockIdx.x * 32;   // src col base
    const int t  = threadIdx.x;
    const int r  = t >> 3;
    const int c4 = (t & 7) * 4;
    float4 v = *reinterpret_cast<const float4*>(src + (size_t)(rb + r) * ldi + cb + c4);
    tile[r][c4 + 0] = v.x; tile[r][c4 + 1] = v.y;
    tile[r][c4 + 2] = v.z; tile[r][c4 + 3] = v.w;
    __syncthreads();
    union { unsigned short us[4]; uint2 v; } pk;
#pragma unroll
    for (int j = 0; j < 4; ++j) pk.us[j] = f2h_bits(tile[c4 + j][r]);
    *reinterpret_cast<uint2*>(dst + (size_t)(cb + r) * ldo + rb + c4) = pk.v;
}

// ---------------------------------------------------------------------------
// Device GEMM tile: C(128 x 16 at col bn) = A(128 x K) @ BT^T, split-K KS=4,
// 16 waves (mw 0..3, kq 0..3). Verified round-5 body (direct loads -> MFMA,
// LDS cross-K reduction). epi: 0 relu(+b1+t@Wt)->f16, 1 relu(+bh)->f16, 2 fp32.
// ---------------------------------------------------------------------------
__device__ __forceinline__ void gemm_phase(
        const unsigned short* __restrict__ A, int lda, int K,
        const unsigned short* __restrict__ BT,
        void* __restrict__ Cout, int ldc,
        const float* __restrict__ biasp, const float* __restrict__ Wtn,
        const float* __restrict__ ts, int sF, int sB,
        int epi, int bn, float (*red)[64][8]) {
    const int tid  = threadIdx.x;
    const int lane = tid & 63;
    const int mw   = (tid >> 6) & 3;
    const int kq   = tid >> 8;       // 0..3
    const int fl   = lane & 15;
    const int qd   = lane >> 4;

    const int Kq = K >> 2;
    const unsigned short* pa0 = A + (size_t)(mw * 32 + fl) * lda + kq * Kq + qd * 8;
    const unsigned short* pa1 = pa0 + (size_t)16 * lda;
    const unsigned short* pb  = BT + (size_t)(bn + fl) * K + kq * Kq + qd * 8;

    floatx4 acc0 = {0.f, 0.f, 0.f, 0.f};
    floatx4 acc1 = {0.f, 0.f, 0.f, 0.f};

    for (int k0 = 0; k0 < Kq; k0 += 128) {
#pragma unroll
        for (int u = 0; u < 4; ++u) {
            halfx8 a0 = *reinterpret_cast<const halfx8*>(pa0 + u * 32);
            halfx8 a1 = *reinterpret_cast<const halfx8*>(pa1 + u * 32);
            halfx8 b  = *reinterpret_cast<const halfx8*>(pb  + u * 32);
            acc0 = __builtin_amdgcn_mfma_f32_16x16x32_f16(a0, b, acc0, 0, 0, 0);
            acc1 = __builtin_amdgcn_mfma_f32_16x16x32_f16(a1, b, acc1, 0, 0, 0);
        }
        pa0 += 128; pa1 += 128; pb += 128;
    }

    if (kq > 0) {
        float* p = &red[(kq - 1) * 4 + mw][lane][0];
#pragma unroll
        for (int j = 0; j < 4; ++j) { p[j] = acc0[j]; p[j + 4] = acc1[j]; }
    }
    __syncthreads();
    if (kq == 0) {
#pragma unroll
        for (int q = 0; q < 3; ++q) {
            const float* p = &red[q * 4 + mw][lane][0];
#pragma unroll
            for (int j = 0; j < 4; ++j) { acc0[j] += p[j]; acc1[j] += p[j + 4]; }
        }
        const int col = bn + fl;
#pragma unroll
        for (int fn = 0; fn < 2; ++fn) {
            floatx4 a = (fn == 0) ? acc0 : acc1;
            const int row_base = mw * 32 + fn * 16 + qd * 4;
#pragma unroll
            for (int rr = 0; rr < 4; ++rr) {
                int row = row_base + rr;
                float v = a[rr];
                if (epi == 0) {
                    int sidx = (row < 64) ? sF : sB;
                    v += biasp[col] + ts[2 * sidx] * Wtn[col] + ts[2 * sidx + 1] * Wtn[HH + col];
                    v = fmaxf(v, 0.f);
                    ((unsigned short*)Cout)[(size_t)row * ldc + col] = f2h_bits(v);
                } else if (epi == 1) {
                    v = fmaxf(v + biasp[col], 0.f);
                    ((unsigned short*)Cout)[(size_t)row * ldc + col] = f2h_bits(v);
                } else {
                    ((float*)Cout)[(size_t)row * ldc + col] = v;
                }
            }
        }
    }
    __syncthreads();   // protect red for next call
}

// ---------------------------------------------------------------------------
// Persistent cooperative kernel: runs all NSS*4 substeps with grid.sync()
// between phases (1 launch instead of 400). grid = 256 x 1024thr (16 waves),
// 1 block/CU co-resident. __threadfence() (agent scope -> cross-XCD L2
// wb/inv on gfx9 multi-XCD) around each grid.sync for coherence (G16).
// ---------------------------------------------------------------------------
struct PKArgs {
    const unsigned short *BT1a, *BT1b, *BTha, *BThb, *BT3a, *BT3b;
    unsigned short *Abuf, *h1, *h2;
    float *STQ, *pos, *mom, *sld;
    const float *b1, *bh, *Wt, *ts;
    const float *bs, *cs, *btr, *bq, *cq, *eps, *masks;
};

__global__ __launch_bounds__(1024, 4) void persistent_kernel(PKArgs a) {
    cg::grid_group grid = cg::this_grid();
    __shared__ float red[12][64][8];   // 24 KB split-K reduction
    __shared__ float redf[16];

    const int tid = threadIdx.x;
    const int bid = blockIdx.x;

    for (int i = 0; i < NSS; ++i) {
        const int sF = i, sB = NSS - 1 - i;
        for (int subidx = 0; subidx < 4; ++subidx) {
            const bool isMom = (subidx == 0 || subidx == 3);
            const int sub = (subidx == 1) ? 2 : 3;
            const unsigned short* B1 = isMom ? a.BT1b : a.BT1a;
            const unsigned short* Bh = isMom ? a.BThb : a.BTha;
            const unsigned short* B3 = isMom ? a.BT3b : a.BT3a;
            const int n = isMom ? 1 : 0;

            // --- GEMM1: h1 = relu(Abuf @ W1|W2 + b1 + t@Wt), N=4096 ---
            gemm_phase(a.Abuf, 2 * DD, 2 * DD, B1, a.h1, HH,
                       a.b1 + n * HH, a.Wt + n * 2 * HH, a.ts, sF, sB,
                       0, bid * 16, red);
            __threadfence(); grid.sync(); __threadfence();

            // --- GEMM2: h2 = relu(h1 @ Wh + bh), N=4096 ---
            gemm_phase(a.h1, HH, HH, Bh, a.h2, HH,
                       a.bh + n * HH, nullptr, a.ts, sF, sB,
                       1, bid * 16, red);
            __threadfence(); grid.sync(); __threadfence();

            // --- GEMM3: STQ = h2 @ [Ws|Wtr|Wq], N=6144 (384 tiles, 2 rounds) ---
            gemm_phase(a.h2, HH, HH, B3, a.STQ, 3 * DD,
                       nullptr, nullptr, a.ts, sF, sB, 2, bid * 16, red);
            if (bid < 128)
                gemm_phase(a.h2, HH, HH, B3, a.STQ, 3 * DD,
                           nullptr, nullptr, a.ts, sF, sB, 2, (256 + bid) * 16, red);
            __threadfence(); grid.sync(); __threadfence();

            // --- update phase: block covers half a row; 1 elem/thread ---
            {
                const int r = bid >> 1;
                const int d = ((bid & 1) << 10) + tid;
                const float e = a.eps[0];
                const int off = isMom ? DD : 0;
                const size_t ro = (size_t)r * 6144;
                float S = tanhf(a.STQ[ro + d] + a.bs[off + d]) * expf(a.cs[off + d]);
                float T = a.STQ[ro + 2048 + d] + a.btr[off + d];
                float Q = tanhf(a.STQ[ro + 4096 + d] + a.bq[off + d]) * expf(a.cq[off + d]);
                const size_t idx = (size_t)r * 2048 + d;
                float ld;
                if (isMom) {
                    float p = a.pos[idx], v = a.mom[idx];
                    float g = sinf(p);
                    float tr = e * Q, sc;
                    if (r < 64) { sc = 0.5f * e * S;  v = v * expf(sc) - 0.5f * e * (expf(tr) * g - T); }
                    else        { sc = -0.5f * e * S; v = expf(sc) * (v + 0.5f * e * (expf(tr) * g - T)); }
                    a.mom[idx] = v;
                    if (subidx == 0) {   // next sub is pos-type with sub==2
                        float m2 = (r < 64) ? a.masks[sF * 2048 + d] : 1.f - a.masks[sB * 2048 + d];
                        a.Abuf[(r << 12) + d]        = f2h_bits(v);
                        a.Abuf[(r << 12) + 2048 + d] = f2h_bits(m2 * p);
                    }
                    ld = sc;
                } else {
                    float p = a.pos[idx], v = a.mom[idx];
                    float sc = e * S, tr = e * Q;
                    float mf = a.masks[sF * 2048 + d], mb = a.masks[sB * 2048 + d];
                    float pn;
                    if (r < 64) {
                        float m  = (sub == 2) ? mf : 1.f - mf;
                        float mi = 1.f - m;
                        pn = m * p + mi * (p * expf(sc) + e * (expf(tr) * v + T));
                        ld = mi * sc;
                    } else {
                        float m  = (sub == 2) ? 1.f - mb : mb;
                        float mi = 1.f - m;
                        pn = m * p + mi * expf(sc) * (p - e * (expf(tr) * v + T));
                        ld = mi * sc;
                    }
                    a.pos[idx] = pn;
                    if (sub == 2) {   // next sub is pos-type with sub==3
                        float m3 = (r < 64) ? 1.f - mf : mb;
                        a.Abuf[(r << 12) + d]        = f2h_bits(v);
                        a.Abuf[(r << 12) + 2048 + d] = f2h_bits(m3 * pn);
                    } else {          // next sub is mom-type
                        a.Abuf[(r << 12) + d]        = f2h_bits(pn);
                        a.Abuf[(r << 12) + 2048 + d] = f2h_bits(sinf(pn));
                    }
                }
                // block reduce (1024 thr) -> one atomic
                for (int o = 32; o; o >>= 1) ld += __shfl_down(ld, o, 64);
                if ((tid & 63) == 0) redf[tid >> 6] = ld;
                __syncthreads();
                if (tid == 0) {
                    float s = 0.f;
#pragma unroll
                    for (int wv = 0; wv < 16; ++wv) s += redf[wv];
                    atomicAdd(a.sld + r, s);
                }
                __syncthreads();
            }
            __threadfence(); grid.sync(); __threadfence();
        }
    }
}

// ---------------------------------------------------------------------------
// Fallback standalone split-K GEMM (harness-verified round-5 kernel)
// ---------------------------------------------------------------------------
template <int EPI, int KS>
__global__ __launch_bounds__(KS * 256, 4) void gemm_bt_kernel(
        const unsigned short* __restrict__ A, int lda, int K,
        const unsigned short* __restrict__ BT,
        void* __restrict__ Cout, int ldc,
        const float* __restrict__ biasp, const float* __restrict__ Wtn,
        const float* __restrict__ ts, int sF, int sB) {
    const int tid  = threadIdx.x;
    const int lane = tid & 63;
    const int mw   = (tid >> 6) & 3;
    const int kq   = tid >> 8;
    const int fl   = lane & 15;
    const int qd   = lane >> 4;
    const int bn   = blockIdx.x * 16;

    const int Kq = K / KS;
    const unsigned short* pa0 = A + (size_t)(mw * 32 + fl) * lda + kq * Kq + qd * 8;
    const unsigned short* pa1 = pa0 + (size_t)16 * lda;
    const unsigned short* pb  = BT + (size_t)(bn + fl) * K + kq * Kq + qd * 8;

    floatx4 acc0 = {0.f, 0.f, 0.f, 0.f};
    floatx4 acc1 = {0.f, 0.f, 0.f, 0.f};

    for (int k0 = 0; k0 < Kq; k0 += 128) {
#pragma unroll
        for (int u = 0; u < 4; ++u) {
            halfx8 a0 = *reinterpret_cast<const halfx8*>(pa0 + u * 32);
            halfx8 a1 = *reinterpret_cast<const halfx8*>(pa1 + u * 32);
            halfx8 b  = *reinterpret_cast<const halfx8*>(pb  + u * 32);
            acc0 = __builtin_amdgcn_mfma_f32_16x16x32_f16(a0, b, acc0, 0, 0, 0);
            acc1 = __builtin_amdgcn_mfma_f32_16x16x32_f16(a1, b, acc1, 0, 0, 0);
        }
        pa0 += 128; pa1 += 128; pb += 128;
    }

    __shared__ float red[(KS - 1) * 4][64][8];
    if (kq > 0) {
        float* p = &red[(kq - 1) * 4 + mw][lane][0];
#pragma unroll
        for (int j = 0; j < 4; ++j) { p[j] = acc0[j]; p[j + 4] = acc1[j]; }
    }
    __syncthreads();
    if (kq != 0) return;
#pragma unroll
    for (int q = 0; q < KS - 1; ++q) {
        const float* p = &red[q * 4 + mw][lane][0];
#pragma unroll
        for (int j = 0; j < 4; ++j) { acc0[j] += p[j]; acc1[j] += p[j + 4]; }
    }

    const int col = bn + fl;
#pragma unroll
    for (int fn = 0; fn < 2; ++fn) {
        floatx4 a = (fn == 0) ? acc0 : acc1;
        const int row_base = mw * 32 + fn * 16 + qd * 4;
#pragma unroll
        for (int rr = 0; rr < 4; ++rr) {
            int row = row_base + rr;
            float v = a[rr];
            if (EPI == 0) {
                int sidx = (row < 64) ? sF : sB;
                v += biasp[col] + ts[2 * sidx] * Wtn[col] + ts[2 * sidx + 1] * Wtn[HH + col];
                v = fmaxf(v, 0.f);
                ((unsigned short*)Cout)[(size_t)row * ldc + col] = f2h_bits(v);
            } else if (EPI == 1) {
                v = fmaxf(v + biasp[col], 0.f);
                ((unsigned short*)Cout)[(size_t)row * ldc + col] = f2h_bits(v);
            } else {
                ((float*)Cout)[(size_t)row * ldc + col] = v;
            }
        }
    }
}

// ---------------------------------------------------------------------------
// Fallback GEMM (reads fp32 weights directly). BM=32,BN=64,BK=32.
// ---------------------------------------------------------------------------
template <int BMODE, int EPI>
__global__ __launch_bounds__(256) void gemm_kernel(
        const unsigned short* __restrict__ A, int lda, int K,
        const float* __restrict__ Bp0, const float* __restrict__ Bp1,
        const float* __restrict__ Bp2, int ldb,
        void* __restrict__ Cout, int ldc,
        const float* __restrict__ biasp, const float* __restrict__ Wtn,
        const float* __restrict__ ts, int sF, int sB) {
    __shared__ unsigned short As[32][40];
    __shared__ unsigned short Bs[64][40];

    const int tid  = threadIdx.x;
    const int wave = tid >> 6;
    const int lane = tid & 63;
    const int fl   = lane & 15;
    const int qd   = lane >> 4;
    const int bm   = blockIdx.y * 32;
    const int bn   = blockIdx.x * 64;
    const int wm   = (wave >> 1) * 16;
    const int wn   = (wave & 1) * 32;

    const int ar = tid >> 3;
    const int ak = (tid & 7) * 4;
    const int kloc = wave * 8;
    const int bnl  = lane;

    floatx4 acc0 = {0.f, 0.f, 0.f, 0.f};
    floatx4 acc1 = {0.f, 0.f, 0.f, 0.f};

    for (int k0 = 0; k0 < K; k0 += 32) {
        *reinterpret_cast<uint2*>(&As[ar][ak]) =
            *reinterpret_cast<const uint2*>(A + (size_t)(bm + ar) * lda + k0 + ak);

        float fv[8];
        if (BMODE == 0) {
            int kk = k0 + kloc;
            const float* base = (kk < 2048) ? (Bp0 + (size_t)kk * ldb)
                                            : (Bp1 + (size_t)(kk - 2048) * ldb);
            base += bn + bnl;
#pragma unroll
            for (int j = 0; j < 8; ++j) fv[j] = base[(size_t)j * ldb];
        } else if (BMODE == 1) {
            const float* base = Bp0 + (size_t)(k0 + kloc) * ldb + bn + bnl;
#pragma unroll
            for (int j = 0; j < 8; ++j) fv[j] = base[(size_t)j * ldb];
        } else {
            int third = bn >> 11;
            const float* Bsel = (third == 0) ? Bp0 : ((third == 1) ? Bp1 : Bp2);
            const float* base = Bsel + (size_t)(k0 + kloc) * ldb + (bn - (third << 11)) + bnl;
#pragma unroll
            for (int j = 0; j < 8; ++j) fv[j] = base[(size_t)j * ldb];
        }
        union { unsigned short us[8]; uint4 v; } pk;
#pragma unroll
        for (int j = 0; j < 8; ++j) pk.us[j] = f2h_bits(fv[j]);
        *reinterpret_cast<uint4*>(&Bs[bnl][kloc]) = pk.v;

        __syncthreads();

        halfx8 afr = *reinterpret_cast<const halfx8*>(&As[wm + fl][qd * 8]);
        halfx8 bf0 = *reinterpret_cast<const halfx8*>(&Bs[wn + fl][qd * 8]);
        halfx8 bf1 = *reinterpret_cast<const halfx8*>(&Bs[wn + 16 + fl][qd * 8]);
        acc0 = __builtin_amdgcn_mfma_f32_16x16x32_f16(afr, bf0, acc0, 0, 0, 0);
        acc1 = __builtin_amdgcn_mfma_f32_16x16x32_f16(afr, bf1, acc1, 0, 0, 0);

        __syncthreads();
    }

    const int row0 = bm + wm + qd * 4;
#pragma unroll
    for (int fn = 0; fn < 2; ++fn) {
        floatx4 a = (fn == 0) ? acc0 : acc1;
        int col = bn + wn + fn * 16 + fl;
#pragma unroll
        for (int rr = 0; rr < 4; ++rr) {
            int row = row0 + rr;
            float v = a[rr];
            if (EPI == 0) {
                int sidx = (row < 64) ? sF : sB;
                v += biasp[col] + ts[2 * sidx] * Wtn[col] + ts[2 * sidx + 1] * Wtn[HH + col];
                v = fmaxf(v, 0.f);
                ((unsigned short*)Cout)[(size_t)row * ldc + col] = f2h_bits(v);
            } else if (EPI == 1) {
                v = fmaxf(v + biasp[col], 0.f);
                ((unsigned short*)Cout)[(size_t)row * ldc + col] = f2h_bits(v);
            } else {
                ((float*)Cout)[(size_t)row * ldc + col] = v;
            }
        }
    }
}

// ---------------------------------------------------------------------------
__device__ __forceinline__ void block_reduce_atomic(float v, float* dst) {
    for (int off = 32; off; off >>= 1) v += __shfl_down(v, off, 64);
    __shared__ float red[4];
    if ((threadIdx.x & 63) == 0) red[threadIdx.x >> 6] = v;
    __syncthreads();
    if (threadIdx.x == 0) atomicAdd(dst, red[0] + red[1] + red[2] + red[3]);
}

// ---------------------------------------------------------------------------
// fallback fused update kernels
// ---------------------------------------------------------------------------
__global__ void update_mom_kernel(const float* __restrict__ pos, float* __restrict__ mom,
                                  float* __restrict__ sld, const float* __restrict__ STQ,
                                  const float* __restrict__ bs, const float* __restrict__ cs,
                                  const float* __restrict__ btr, const float* __restrict__ bq,
                                  const float* __restrict__ cq, const float* __restrict__ eps,
                                  const float* __restrict__ masks, int sF, int sB,
                                  int writeNext, unsigned short* __restrict__ Abuf) {
    int r = blockIdx.y;
    int d = blockIdx.x * 256 + threadIdx.x;
    float e = eps[0];
    size_t ro = (size_t)r * 6144;
    float S = tanhf(STQ[ro + d] + bs[d]) * expf(cs[d]);
    float T = STQ[ro + 2048 + d] + btr[d];
    float Q = tanhf(STQ[ro + 4096 + d] + bq[d]) * expf(cq[d]);
    size_t idx = (size_t)r * 2048 + d;
    float p = pos[idx], v = mom[idx];
    float g = sinf(p);
    float tr = e * Q, sc;
    if (r < 64) { sc = 0.5f * e * S;  v = v * expf(sc) - 0.5f * e * (expf(tr) * g - T); }
    else        { sc = -0.5f * e * S; v = expf(sc) * (v + 0.5f * e * (expf(tr) * g - T)); }
    mom[idx] = v;
    if (writeNext) {
        float m2 = (r < 64) ? masks[sF * 2048 + d] : 1.f - masks[sB * 2048 + d];
        Abuf[(r << 12) + d]        = f2h_bits(v);
        Abuf[(r << 12) + 2048 + d] = f2h_bits(m2 * p);
    }
    block_reduce_atomic(sc, sld + r);
}

__global__ void update_pos_kernel(float* __restrict__ pos, const float* __restrict__ mom,
                                  float* __restrict__ sld, const float* __restrict__ STQ,
                                  const float* __restrict__ bs, const float* __restrict__ cs,
                                  const float* __restrict__ btr, const float* __restrict__ bq,
                                  const float* __restrict__ cq, const float* __restrict__ eps,
                                  const float* __restrict__ masks, int sF, int sB, int sub,
                                  unsigned short* __restrict__ Abuf) {
    int r = blockIdx.y;
    int d = blockIdx.x * 256 + threadIdx.x;
    float e = eps[0];
    size_t ro = (size_t)r * 6144;
    float S = tanhf(STQ[ro + d] + bs[d]) * expf(cs[d]);
    float T = STQ[ro + 2048 + d] + btr[d];
    float Q = tanhf(STQ[ro + 4096 + d] + bq[d]) * expf(cq[d]);
    size_t idx = (size_t)r * 2048 + d;
    float p = pos[idx], v = mom[idx];
    float sc = e * S, tr = e * Q;
    float mf = masks[sF * 2048 + d], mb = masks[sB * 2048 + d];
    float pn, ld;
    if (r < 64) {
        float m  = (sub == 2) ? mf : 1.f - mf;
        float mi = 1.f - m;
        pn = m * p + mi * (p * expf(sc) + e * (expf(tr) * v + T));
        ld = mi * sc;
    } else {
        float m  = (sub == 2) ? 1.f - mb : mb;
        float mi = 1.f - m;
        pn = m * p + mi * expf(sc) * (p - e * (expf(tr) * v + T));
        ld = mi * sc;
    }
    pos[idx] = pn;
    if (sub == 2) {
        float m3 = (r < 64) ? 1.f - mf : mb;
        Abuf[(r << 12) + d]        = f2h_bits(v);
        Abuf[(r << 12) + 2048 + d] = f2h_bits(m3 * pn);
    } else {
        Abuf[(r << 12) + d]        = f2h_bits(pn);
        Abuf[(r << 12) + 2048 + d] = f2h_bits(sinf(pn));
    }
    block_reduce_atomic(ld, sld + r);
}

// ---------------------------------------------------------------------------
__global__ void accept_kernel(const float* __restrict__ position,
                              const float* __restrict__ momf, const float* __restrict__ momb,
                              const float* __restrict__ pos, const float* __restrict__ mom,
                              const float* __restrict__ sld, float* __restrict__ ap_all) {
    int r = blockIdx.x;
    int rb = r & 63;
    const float* m0 = (r < 64) ? (momf + (size_t)rb * 2048) : (momb + (size_t)rb * 2048);
    float s = 0.f;
    for (int d = threadIdx.x; d < 2048; d += 256) {
        float x0 = position[rb * 2048 + d];
        float v0 = m0[d];
        float x1 = pos[(size_t)r * 2048 + d];
        float v1 = mom[(size_t)r * 2048 + d];
        s += (cosf(x1) - cosf(x0)) + 0.5f * (v0 * v0 - v1 * v1);
    }
    for (int off = 32; off; off >>= 1) s += __shfl_down(s, off, 64);
    __shared__ float red[4];
    if ((threadIdx.x & 63) == 0) red[threadIdx.x >> 6] = s;
    __syncthreads();
    if (threadIdx.x == 0) {
        float dd = red[0] + red[1] + red[2] + red[3] + sld[r];
        float p = isnan(dd) ? 0.f : expf(dd < 0.f ? dd : 0.f);
        if (!isfinite(p)) p = 0.f;
        ap_all[r] = p;
    }
}

// ---------------------------------------------------------------------------
__global__ void combine_kernel(const float* __restrict__ position,
                               const float* __restrict__ u_dir, const float* __restrict__ u_accept,
                               const float* __restrict__ pos, const float* __restrict__ mom,
                               const float* __restrict__ ap_all, float* __restrict__ out) {
    int idx = blockIdx.x * 256 + threadIdx.x;  // over BD*DD
    int b = idx >> 11, d = idx & 2047;
    float fm = (u_dir[b] > 0.5f) ? 1.f : 0.f;
    float pf = pos[(size_t)b * 2048 + d],       pb = pos[(size_t)(64 + b) * 2048 + d];
    float mf = mom[(size_t)b * 2048 + d],       mb = mom[(size_t)(64 + b) * 2048 + d];
    float ppost = fm * pf + (1.f - fm) * pb;
    float mpost = fm * mf + (1.f - fm) * mb;
    float ap = fm * ap_all[b] + (1.f - fm) * ap_all[64 + b];
    float am = (ap > u_accept[b]) ? 1.f : 0.f;
    out[idx] = ppost;
    out[131072 + idx] = mpost;
    if (d == 0) out[262144 + b] = ap;
    out[262208 + idx] = am * ppost + (1.f - am) * position[idx];
}

// ---------------------------------------------------------------------------
extern "C" void kernel_launch(void* const* d_in, const int* in_sizes, int n_in,
                              void* d_out, int out_size, void* d_ws, size_t ws_size,
                              hipStream_t stream) {
    const float* position   = (const float*)d_in[0];
    const float* momentum_f = (const float*)d_in[1];
    const float* momentum_b = (const float*)d_in[2];
    const float* u_dir      = (const float*)d_in[3];
    const float* u_accept   = (const float*)d_in[4];
    const float* eps        = (const float*)d_in[5];
    const float* masks      = (const float*)d_in[6];
    const float* ts         = (const float*)d_in[7];
    const float* W1         = (const float*)d_in[8];
    const float* W2         = (const float*)d_in[9];
    const float* Wt         = (const float*)d_in[10];
    const float* b1         = (const float*)d_in[11];
    const float* Wh         = (const float*)d_in[12];
    const float* bh         = (const float*)d_in[13];
    const float* Ws         = (const float*)d_in[14];
    const float* bs         = (const float*)d_in[15];
    const float* cs         = (const float*)d_in[16];
    const float* Wtr        = (const float*)d_in[17];
    const float* btr        = (const float*)d_in[18];
    const float* Wq         = (const float*)d_in[19];
    const float* bq         = (const float*)d_in[20];
    const float* cq         = (const float*)d_in[21];
    float* out = (float*)d_out;

    // ---- workspace carve ----
    float* pos    = (float*)d_ws;               // 128*2048
    float* mom    = pos + BBr * DD;
    float* sld    = mom + BBr * DD;             // 128
    float* ap_all = sld + BBr;                  // 128
    float* STQ    = ap_all + BBr;               // 128*6144
    unsigned short* Abuf = (unsigned short*)(STQ + BBr * 3 * DD);  // 128*4096
    unsigned short* h1   = Abuf + (size_t)BBr * 2 * DD;            // 128*4096
    unsigned short* h2   = h1 + (size_t)BBr * HH;                  // 128*4096
    unsigned short* BTw  = h2 + (size_t)BBr * HH;                  // weights f16

    const size_t BT1sz = (size_t)HH * 2 * DD;
    const size_t BThsz = (size_t)HH * HH;
    const size_t BT3sz = (size_t)3 * DD * HH;
    const size_t perNet = BT1sz + BThsz + BT3sz;
    unsigned short* BT1[2] = { BTw,                 BTw + perNet };
    unsigned short* BTh[2] = { BTw + BT1sz,         BTw + perNet + BT1sz };
    unsigned short* BT3[2] = { BTw + BT1sz + BThsz, BTw + perNet + BT1sz + BThsz };

    const size_t NEED = (size_t)((char*)(BTw + 2 * perNet) - (char*)d_ws);
    const bool fast = (ws_size >= NEED);

    const size_t DH  = (size_t)DD * HH;
    const size_t HH2 = (size_t)HH * HH;

    init_kernel<<<BBr * DD / 256, 256, 0, stream>>>(position, momentum_f, momentum_b,
                                                    pos, mom, sld, Abuf);

    if (fast) {
        for (int n = 0; n < 2; ++n) {
            transpose_cvt_kernel<<<dim3(HH / 32, DD / 32), 256, 0, stream>>>(
                W1 + n * DH, HH, BT1[n], 2 * DD);
            transpose_cvt_kernel<<<dim3(HH / 32, DD / 32), 256, 0, stream>>>(
                W2 + n * DH, HH, BT1[n] + DD, 2 * DD);
            transpose_cvt_kernel<<<dim3(HH / 32, HH / 32), 256, 0, stream>>>(
                Wh + n * HH2, HH, BTh[n], HH);
            transpose_cvt_kernel<<<dim3(DD / 32, HH / 32), 256, 0, stream>>>(
                Ws + n * DH, DD, BT3[n], HH);
            transpose_cvt_kernel<<<dim3(DD / 32, HH / 32), 256, 0, stream>>>(
                Wtr + n * DH, DD, BT3[n] + (size_t)DD * HH, HH);
            transpose_cvt_kernel<<<dim3(DD / 32, HH / 32), 256, 0, stream>>>(
                Wq + n * DH, DD, BT3[n] + (size_t)2 * DD * HH, HH);
        }
    }

    bool coopDone = false;
    if (fast) {
        int nb = 0;
        hipError_t occErr = hipOccupancyMaxActiveBlocksPerMultiprocessor(
            &nb, persistent_kernel, 1024, 0);
        if (occErr == hipSuccess && nb >= 1) {
            PKArgs a;
            a.BT1a = BT1[0]; a.BT1b = BT1[1];
            a.BTha = BTh[0]; a.BThb = BTh[1];
            a.BT3a = BT3[0]; a.BT3b = BT3[1];
            a.Abuf = Abuf; a.h1 = h1; a.h2 = h2;
            a.STQ = STQ; a.pos = pos; a.mom = mom; a.sld = sld;
            a.b1 = b1; a.bh = bh; a.Wt = Wt; a.ts = ts;
            a.bs = bs; a.cs = cs; a.btr = btr; a.bq = bq; a.cq = cq;
            a.eps = eps; a.masks = masks;
            void* kargs[] = { &a };
            hipError_t ce = hipLaunchCooperativeKernel(
                (const void*)persistent_kernel, dim3(256), dim3(1024), kargs, 0, stream);
            coopDone = (ce == hipSuccess);
        }
    }

    if (!coopDone) {
        for (int i = 0; i < NSS; ++i) {
            int sF = i, sB = NSS - 1 - i;
            for (int subidx = 0; subidx < 4; ++subidx) {
                bool isMom = (subidx == 0 || subidx == 3);
                int n = isMom ? 1 : 0;
                int sub = (subidx == 1) ? 2 : 3;

                if (fast) {
                    gemm_bt_kernel<0, 4><<<HH / 16, 1024, 0, stream>>>(
                        Abuf, 2 * DD, 2 * DD, BT1[n], h1, HH,
                        b1 + n * HH, Wt + n * 2 * HH, ts, sF, sB);
                    gemm_bt_kernel<1, 4><<<HH / 16, 1024, 0, stream>>>(
                        h1, HH, HH, BTh[n], h2, HH,
                        bh + n * HH, nullptr, ts, sF, sB);
                    gemm_bt_kernel<2, 2><<<3 * DD / 16, 512, 0, stream>>>(
                        h2, HH, HH, BT3[n], STQ, 3 * DD,
                        nullptr, nullptr, ts, sF, sB);
                } else {
                    gemm_kernel<0, 0><<<dim3(HH / 64, 4), 256, 0, stream>>>(
                        Abuf, 2 * DD, 2 * DD,
                        W1 + n * DH, W2 + n * DH, nullptr, HH, h1, HH,
                        b1 + n * HH, Wt + n * 2 * HH, ts, sF, sB);
                    gemm_kernel<1, 1><<<dim3(HH / 64, 4), 256, 0, stream>>>(
                        h1, HH, HH, Wh + n * HH2, nullptr, nullptr, HH, h2, HH,
                        bh + n * HH, nullptr, ts, sF, sB);
                    gemm_kernel<2, 2><<<dim3(3 * DD / 64, 4), 256, 0, stream>>>(
                        h2, HH, HH, Ws + n * DH, Wtr + n * DH, Wq + n * DH, DD, STQ, 3 * DD,
                        nullptr, nullptr, ts, sF, sB);
                }

                if (isMom)
                    update_mom_kernel<<<dim3(DD / 256, BBr), 256, 0, stream>>>(
                        pos, mom, sld, STQ, bs + DD, cs + DD, btr + DD, bq + DD, cq + DD,
                        eps, masks, sF, sB, (subidx == 0) ? 1 : 0, Abuf);
                else
                    update_pos_kernel<<<dim3(DD / 256, BBr), 256, 0, stream>>>(
                        pos, mom, sld, STQ, bs, cs, btr, bq, cq, eps, masks, sF, sB, sub, Abuf);
            }
        }
    }

    accept_kernel<<<BBr, 256, 0, stream>>>(position, momentum_f, momentum_b,
                                           pos, mom, sld, ap_all);
    combine_kernel<<<BD * DD / 256, 256, 0, stream>>>(position, u_dir, u_accept,
                                                      pos, mom, ap_all, out);
}